// Round 1
// baseline (658.963 us; speedup 1.0000x reference)
//
#include <hip/hip_runtime.h>
#include <stdint.h>

// ---------------------------------------------------------------------------
// CPMAntAttention: B=2,S=1024,D=4096,H=32,DH=128
// Pipeline: canon_mask -> cvt hidden to bf16 -> [transpose W -> GEMM] x4
//           with flash attention between GEMM3 and GEMM4.
// ---------------------------------------------------------------------------

#define B_  2
#define S_  1024
#define D_  4096
#define H_  32
#define DH_ 128
#define M_  (B_ * S_)          // 2048

typedef __attribute__((ext_vector_type(8))) short bf16x8;
typedef __attribute__((ext_vector_type(4))) float f32x4;

static __device__ __forceinline__ unsigned short f32_to_bf16(float f) {
    unsigned int x = __float_as_uint(f);
    x += 0x7fffu + ((x >> 16) & 1u);   // RNE
    return (unsigned short)(x >> 16);
}

static __device__ __forceinline__ f32x4 mfma16(bf16x8 a, bf16x8 b, f32x4 c) {
    return __builtin_amdgcn_mfma_f32_16x16x32_bf16(a, b, c, 0, 0, 0);
}

#if defined(__has_builtin)
#if __has_builtin(__builtin_amdgcn_global_load_lds)
#define HAVE_GLOAD_LDS 1
#endif
#endif

#ifdef HAVE_GLOAD_LDS
// wave-uniform LDS base; HW adds lane*16B. Global src is per-lane.
#define GLD16(g, lbase, lane)                                                  \
    __builtin_amdgcn_global_load_lds(                                          \
        (const __attribute__((address_space(1))) void*)(g),                    \
        (__attribute__((address_space(3))) void*)(lbase), 16, 0, 0)
#else
#define GLD16(g, lbase, lane)                                                  \
    do { *(bf16x8*)((unsigned short*)(lbase) + (size_t)(lane) * 8) =           \
             *(const bf16x8*)(g); } while (0)
#endif

// ---------------------------------------------------------------------------
// mask dtype detection: 0 = u8/bool, 1 = int32, 2 = float32
__global__ void detect_mask_kernel(const unsigned char* __restrict__ m, int* flag) {
    if (threadIdx.x != 0 || blockIdx.x != 0) return;
    int nz_hi = 0, nz_lo01 = 0;
    for (int i = 0; i < 1024; ++i) {
        unsigned char v = m[i];
        if (v && (i & 3) != 0) nz_hi = 1;     // any nonzero byte off the int32 LSB
        if (v && (i & 3) <= 1) nz_lo01 = 1;   // bytes 0/1 of each 4-group
    }
    int f;
    if (!nz_hi) f = 1;          // [v,0,0,0] pattern -> int32 LE
    else if (!nz_lo01) f = 2;   // [0,0,80,3f] pattern -> float32
    else f = 0;                 // random 0/1 bytes -> bool/u8
    *flag = f;
}

__global__ void canon_mask_kernel(const void* __restrict__ m, const int* __restrict__ flag,
                                  unsigned char* __restrict__ out, int n) {
    int i = blockIdx.x * 256 + threadIdx.x;
    if (i >= n) return;
    int f = *flag;
    unsigned char v;
    if (f == 1)      v = (unsigned char)(((const int*)m)[i] != 0);
    else if (f == 2) v = (unsigned char)(((const float*)m)[i] != 0.0f);
    else             v = (unsigned char)(((const unsigned char*)m)[i] != 0);
    out[i] = v;
}

// ---------------------------------------------------------------------------
// fp32 -> bf16 elementwise (n4 = n/4)
__global__ void cvt_bf16_kernel(const float* __restrict__ in, unsigned short* __restrict__ out, int n4) {
    int i = blockIdx.x * 256 + threadIdx.x;
    if (i >= n4) return;
    float4 v = ((const float4*)in)[i];
    ushort4 o;
    o.x = f32_to_bf16(v.x); o.y = f32_to_bf16(v.y);
    o.z = f32_to_bf16(v.z); o.w = f32_to_bf16(v.w);
    ((ushort4*)out)[i] = o;
}

// ---------------------------------------------------------------------------
// W [4096][4096] fp32 -> WT [4096][4096] bf16 (WT[n][k] = W[k][n]); 64x64 tiles
__global__ __launch_bounds__(256) void transpose_w_kernel(const float* __restrict__ W,
                                                          unsigned short* __restrict__ WT) {
    __shared__ unsigned short lds[64][65];
    int bx = blockIdx.x & 63;    // n tile
    int by = blockIdx.x >> 6;    // k tile
    int t = threadIdx.x;
    int tr = t >> 4;             // 0..15
    int tc = (t & 15) * 4;       // 0..60
#pragma unroll
    for (int p = 0; p < 4; ++p) {
        int r = p * 16 + tr;
        float4 v = *(const float4*)(W + (size_t)(by * 64 + r) * D_ + bx * 64 + tc);
        lds[r][tc + 0] = f32_to_bf16(v.x);
        lds[r][tc + 1] = f32_to_bf16(v.y);
        lds[r][tc + 2] = f32_to_bf16(v.z);
        lds[r][tc + 3] = f32_to_bf16(v.w);
    }
    __syncthreads();
#pragma unroll
    for (int p = 0; p < 4; ++p) {
        int n = p * 16 + tr;
        ushort4 o;
        o.x = lds[tc + 0][n]; o.y = lds[tc + 1][n];
        o.z = lds[tc + 2][n]; o.w = lds[tc + 3][n];
        *(ushort4*)(WT + (size_t)(bx * 64 + n) * D_ + by * 64 + tc) = o;
    }
}

// ---------------------------------------------------------------------------
// GEMM: C[M][N] = A[M][K] * BT[N][K]^T, bf16 inputs, fp32 accum.
// 128x128 tile, BK=64, 4 waves (2x2), 16x16x32 MFMA (m97 structure).
template <int OUT_BF16>
__global__ __launch_bounds__(256, 2) void gemm_kernel(const unsigned short* __restrict__ A,
                                                      const unsigned short* __restrict__ BT,
                                                      void* __restrict__ C, int M, int N, int K) {
    __shared__ unsigned short Atile[128 * 64];
    __shared__ unsigned short Btile[128 * 64];
    int bn_t = N >> 7;
    int bm = (int)blockIdx.x / bn_t;
    int bn = (int)blockIdx.x % bn_t;
    int m0 = bm << 7, n0 = bn << 7;
    int t = threadIdx.x, w = t >> 6, l = t & 63;
    int lr = l & 15, lg = l >> 4;
    int wm = (w >> 1) << 6, wn = (w & 1) << 6;

    f32x4 acc[4][4];
    f32x4 vzero = {0.f, 0.f, 0.f, 0.f};
#pragma unroll
    for (int i = 0; i < 4; ++i)
#pragma unroll
        for (int j = 0; j < 4; ++j) acc[i][j] = vzero;

    int srow = (w << 5) + (l >> 3);      // staging row (+ c*8)
    int scol = (l & 7) << 3;             // staging k-col
    const unsigned short* gA = A + (size_t)(m0 + srow) * K + scol;
    const unsigned short* gB = BT + (size_t)(n0 + srow) * K + scol;

    for (int kt = 0; kt < K; kt += 64) {
        __syncthreads();
#pragma unroll
        for (int c = 0; c < 4; ++c) {
            GLD16(gA + (size_t)(c * 8) * K + kt, &Atile[(((w << 2) + c)) << 9], l);
            GLD16(gB + (size_t)(c * 8) * K + kt, &Btile[(((w << 2) + c)) << 9], l);
        }
        __syncthreads();
#pragma unroll
        for (int kf = 0; kf < 2; ++kf) {
            bf16x8 af[4], bfr[4];
#pragma unroll
            for (int mi = 0; mi < 4; ++mi)
                af[mi] = *(const bf16x8*)&Atile[(wm + mi * 16 + lr) * 64 + kf * 32 + lg * 8];
#pragma unroll
            for (int ni = 0; ni < 4; ++ni)
                bfr[ni] = *(const bf16x8*)&Btile[(wn + ni * 16 + lr) * 64 + kf * 32 + lg * 8];
#pragma unroll
            for (int mi = 0; mi < 4; ++mi)
#pragma unroll
                for (int ni = 0; ni < 4; ++ni)
                    acc[mi][ni] = mfma16(af[mi], bfr[ni], acc[mi][ni]);
        }
    }
#pragma unroll
    for (int mi = 0; mi < 4; ++mi)
#pragma unroll
        for (int ni = 0; ni < 4; ++ni)
#pragma unroll
            for (int r = 0; r < 4; ++r) {
                int row = m0 + wm + mi * 16 + lg * 4 + r;
                int col = n0 + wn + ni * 16 + lr;
                if (OUT_BF16)
                    ((unsigned short*)C)[(size_t)row * N + col] = f32_to_bf16(acc[mi][ni][r]);
                else
                    ((float*)C)[(size_t)row * N + col] = acc[mi][ni][r];
            }
}

// ---------------------------------------------------------------------------
// Flash attention. Grid: B*H*(S/64). Block: 256 thr (4 waves), 16 q-rows/wave.
#define NEGF (-1e30f)
__global__ __launch_bounds__(256, 2) void attn_kernel(const unsigned short* __restrict__ Qw,
                                                      const unsigned short* __restrict__ Kw,
                                                      const unsigned short* __restrict__ Vw,
                                                      const float* __restrict__ bias,
                                                      const unsigned char* __restrict__ maskc,
                                                      unsigned short* __restrict__ ctx) {
    __shared__ unsigned short Kt[64 * 128];   // [kv][dh], 16B-chunk XOR swizzled by kv&7
    __shared__ unsigned short Vt[128 * 64];   // transposed [dh][kv], byte ^ ((dh&7)<<4)
    __shared__ unsigned short Plds[4][16 * 72];

    int bid = blockIdx.x;
    int qt = bid & 15, h = (bid >> 4) & 31, b = bid >> 9;
    int t = threadIdx.x, w = t >> 6, l = t & 63;
    int lr = l & 15, lg = l >> 4;
    int q0 = (qt << 6) + (w << 4);

    // Q fragments (A-operand rows lr)
    bf16x8 qf[4];
    const unsigned short* Qp = Qw + ((size_t)(b * S_ + q0 + lr)) * D_ + h * DH_ + lg * 8;
#pragma unroll
    for (int kf = 0; kf < 4; ++kf) qf[kf] = *(const bf16x8*)(Qp + kf * 32);

    f32x4 o[8];
    f32x4 vzero = {0.f, 0.f, 0.f, 0.f};
#pragma unroll
    for (int i = 0; i < 8; ++i) o[i] = vzero;
    float m_run[4], l_run[4];
#pragma unroll
    for (int r = 0; r < 4; ++r) { m_run[r] = NEGF; l_run[r] = 0.f; }

    const float* biasp = bias + (((size_t)(b * H_ + h)) << 20);
    const unsigned char* mp = maskc + ((size_t)b << 20);

    for (int kt = 0; kt < 16; ++kt) {
        int kv0 = kt << 6;
        __syncthreads();   // prev tile's LDS reads done
        // --- stage K (global_load_lds, source pre-swizzled so reads are conflict-free)
#pragma unroll
        for (int c = 0; c < 4; ++c) {
            int slot = (((w << 2) + c) << 6) + l;       // 16B-chunk index 0..1023
            int krow = slot >> 4;                       // 0..63
            int chunk = (slot & 15) ^ (krow & 7);
            const unsigned short* g =
                Kw + ((size_t)(b * S_ + kv0 + krow)) * D_ + h * DH_ + (chunk << 3);
            GLD16(g, &Kt[(((w << 2) + c)) << 9], l);
        }
        // --- stage V transposed (manual, swizzled)
#pragma unroll
        for (int p = 0; p < 4; ++p) {
            int kvl = (p << 4) + (t & 15);
            int dh0 = (t >> 4) << 3;
            bf16x8 v = *(const bf16x8*)(Vw + ((size_t)(b * S_ + kv0 + kvl)) * D_ + h * DH_ + dh0);
#pragma unroll
            for (int j = 0; j < 8; ++j) {
                int dh = dh0 + j;
                int ba = ((dh << 7) + (kvl << 1)) ^ ((dh & 7) << 4);
                *(unsigned short*)((char*)Vt + ba) = (unsigned short)v[j];
            }
        }
        __syncthreads();   // K landed (vmcnt drained by barrier), V transposed

        // --- QK^T
        f32x4 s[4];
#pragma unroll
        for (int nb = 0; nb < 4; ++nb) {
            s[nb] = vzero;
            int krow = (nb << 4) + lr;
#pragma unroll
            for (int kf = 0; kf < 4; ++kf) {
                int ba = ((krow << 8) + ((kf << 5) + (lg << 3)) * 2) ^ ((krow & 7) << 4);
                bf16x8 kfr = *(const bf16x8*)((const char*)Kt + ba);
                s[nb] = mfma16(qf[kf], kfr, s[nb]);
            }
        }

        // --- softmax (online), rows r: q = q0 + lg*4 + r; cols: kv = kv0 + nb*16 + lr
        float sv[4][4];
#pragma unroll
        for (int nb = 0; nb < 4; ++nb)
#pragma unroll
            for (int r = 0; r < 4; ++r) {
                int q = q0 + (lg << 2) + r;
                int kv = kv0 + (nb << 4) + lr;
                float x = s[nb][r] * 0.08838834764831845f + biasp[((size_t)q << 10) + kv];
                sv[nb][r] = mp[((size_t)q << 10) + kv] ? x : NEGF;
            }
        float mt[4], al[4], rs[4];
#pragma unroll
        for (int r = 0; r < 4; ++r)
            mt[r] = fmaxf(fmaxf(sv[0][r], sv[1][r]), fmaxf(sv[2][r], sv[3][r]));
#pragma unroll
        for (int off = 1; off < 16; off <<= 1)
#pragma unroll
            for (int r = 0; r < 4; ++r) mt[r] = fmaxf(mt[r], __shfl_xor(mt[r], off, 64));
#pragma unroll
        for (int r = 0; r < 4; ++r) {
            float mn = fmaxf(m_run[r], mt[r]);
            al[r] = __expf(m_run[r] - mn);
            m_run[r] = mn;
        }
#pragma unroll
        for (int nb = 0; nb < 4; ++nb)
#pragma unroll
            for (int r = 0; r < 4; ++r) sv[nb][r] = __expf(sv[nb][r] - m_run[r]);
#pragma unroll
        for (int r = 0; r < 4; ++r)
            rs[r] = (sv[0][r] + sv[1][r]) + (sv[2][r] + sv[3][r]);
#pragma unroll
        for (int off = 1; off < 16; off <<= 1)
#pragma unroll
            for (int r = 0; r < 4; ++r) rs[r] += __shfl_xor(rs[r], off, 64);
#pragma unroll
        for (int r = 0; r < 4; ++r) l_run[r] = l_run[r] * al[r] + rs[r];
#pragma unroll
        for (int nb2 = 0; nb2 < 8; ++nb2) {
            o[nb2][0] *= al[0]; o[nb2][1] *= al[1];
            o[nb2][2] *= al[2]; o[nb2][3] *= al[3];
        }
        // write P (per-wave private tile)
#pragma unroll
        for (int nb = 0; nb < 4; ++nb)
#pragma unroll
            for (int r = 0; r < 4; ++r)
                Plds[w][((lg << 2) + r) * 72 + (nb << 4) + lr] = f32_to_bf16(sv[nb][r]);

        // --- PV
#pragma unroll
        for (int kf2 = 0; kf2 < 2; ++kf2) {
            bf16x8 pf = *(const bf16x8*)&Plds[w][lr * 72 + (kf2 << 5) + (lg << 3)];
#pragma unroll
            for (int nb2 = 0; nb2 < 8; ++nb2) {
                int dh = (nb2 << 4) + lr;
                int ba = ((dh << 7) + ((kf2 << 5) + (lg << 3)) * 2) ^ ((dh & 7) << 4);
                bf16x8 vf = *(const bf16x8*)((const char*)Vt + ba);
                o[nb2] = mfma16(pf, vf, o[nb2]);
            }
        }
    }

    // epilogue: normalize + store ctx bf16  [b*S+q][h*DH+dh]
#pragma unroll
    for (int r = 0; r < 4; ++r) {
        float inv = l_run[r] > 0.f ? 1.0f / l_run[r] : 0.f;
        int q = q0 + (lg << 2) + r;
        unsigned short* cp = ctx + ((size_t)(b * S_ + q)) * D_ + h * DH_ + lr;
#pragma unroll
        for (int nb2 = 0; nb2 < 8; ++nb2)
            cp[nb2 * 16] = f32_to_bf16(o[nb2][r] * inv);
    }
}

// ---------------------------------------------------------------------------
extern "C" void kernel_launch(void* const* d_in, const int* in_sizes, int n_in,
                              void* d_out, int out_size, void* d_ws, size_t ws_size,
                              hipStream_t stream) {
    const float* hq   = (const float*)d_in[0];
    const float* hkv  = (const float*)d_in[1];
    const void*  mask = d_in[2];
    const float* bias = (const float*)d_in[3];
    const float* Wq   = (const float*)d_in[4];
    const float* Wk   = (const float*)d_in[5];
    const float* Wv   = (const float*)d_in[6];
    const float* Wo   = (const float*)d_in[7];
    float* out = (float*)d_out;

    char* ws = (char*)d_ws;
    unsigned char* mask_c = (unsigned char*)ws;                    // 2 MB
    int* flag            = (int*)(ws + 2097152);                   // 256 B
    unsigned short* hq_b  = (unsigned short*)(ws + 2097408);       // 16 MB
    unsigned short* hkv_b = hq_b + 8388608;                        // 16 MB
    unsigned short* WT    = hkv_b + 8388608;                       // 32 MB
    unsigned short* Qws   = WT + 16777216;                         // 16 MB
    unsigned short* Kws   = Qws + 8388608;                         // 16 MB
    unsigned short* Vws   = Kws + 8388608;                         // 16 MB
    unsigned short* Cws   = Vws + 8388608;                         // 16 MB

    detect_mask_kernel<<<1, 64, 0, stream>>>((const unsigned char*)mask, flag);
    canon_mask_kernel<<<8192, 256, 0, stream>>>(mask, flag, mask_c, B_ * S_ * S_);
    cvt_bf16_kernel<<<8192, 256, 0, stream>>>(hq, hq_b, (B_ * S_ * D_) / 4);
    cvt_bf16_kernel<<<8192, 256, 0, stream>>>(hkv, hkv_b, (B_ * S_ * D_) / 4);

    transpose_w_kernel<<<4096, 256, 0, stream>>>(Wq, WT);
    gemm_kernel<1><<<(M_ / 128) * (D_ / 128), 256, 0, stream>>>(hq_b, WT, Qws, M_, D_, D_);
    transpose_w_kernel<<<4096, 256, 0, stream>>>(Wk, WT);
    gemm_kernel<1><<<(M_ / 128) * (D_ / 128), 256, 0, stream>>>(hkv_b, WT, Kws, M_, D_, D_);
    transpose_w_kernel<<<4096, 256, 0, stream>>>(Wv, WT);
    gemm_kernel<1><<<(M_ / 128) * (D_ / 128), 256, 0, stream>>>(hkv_b, WT, Vws, M_, D_, D_);

    attn_kernel<<<B_ * H_ * (S_ / 64), 256, 0, stream>>>(Qws, Kws, Vws, bias, mask_c, Cws);

    transpose_w_kernel<<<4096, 256, 0, stream>>>(Wo, WT);
    gemm_kernel<0><<<(M_ / 128) * (D_ / 128), 256, 0, stream>>>(Cws, WT, out, M_, D_, D_);
}

// Round 2
// 605.729 us; speedup vs baseline: 1.0879x; 1.0879x over previous
//
#include <hip/hip_runtime.h>
#include <stdint.h>

// ---------------------------------------------------------------------------
// CPMAntAttention: B=2,S=1024,D=4096,H=32,DH=128
// Round 2: latency-hiding attention (reg-prefetched bias/mask, dbuf K/V LDS,
// pre-transposed V), parallel mask-dtype detect. GEMMs unchanged (m97).
// ---------------------------------------------------------------------------

#define B_  2
#define S_  1024
#define D_  4096
#define H_  32
#define DH_ 128
#define M_  (B_ * S_)          // 2048

typedef __attribute__((ext_vector_type(8))) short bf16x8;
typedef __attribute__((ext_vector_type(4))) float f32x4;

static __device__ __forceinline__ unsigned short f32_to_bf16(float f) {
    unsigned int x = __float_as_uint(f);
    x += 0x7fffu + ((x >> 16) & 1u);   // RNE
    return (unsigned short)(x >> 16);
}

static __device__ __forceinline__ f32x4 mfma16(bf16x8 a, bf16x8 b, f32x4 c) {
    return __builtin_amdgcn_mfma_f32_16x16x32_bf16(a, b, c, 0, 0, 0);
}

#if defined(__has_builtin)
#if __has_builtin(__builtin_amdgcn_global_load_lds)
#define HAVE_GLOAD_LDS 1
#endif
#endif

#ifdef HAVE_GLOAD_LDS
// wave-uniform LDS base; HW adds lane*16B. Global src is per-lane.
#define GLD16(g, lbase, lane)                                                  \
    __builtin_amdgcn_global_load_lds(                                          \
        (const __attribute__((address_space(1))) void*)(g),                    \
        (__attribute__((address_space(3))) void*)(lbase), 16, 0, 0)
#else
#define GLD16(g, lbase, lane)                                                  \
    do { *(bf16x8*)((unsigned short*)(lbase) + (size_t)(lane) * 8) =           \
             *(const bf16x8*)(g); } while (0)
#endif

// ---------------------------------------------------------------------------
// mask dtype detection: 0 = u8/bool, 1 = int32, 2 = float32. 64 lanes, 1 uint4 each.
__global__ void detect_mask_kernel(const unsigned char* __restrict__ m, int* flag) {
    int l = threadIdx.x;               // 0..63
    uint4 v = ((const uint4*)m)[l];    // bytes l*16 .. l*16+15
    unsigned int ww[4] = {v.x, v.y, v.z, v.w};
    int nz_hi = 0, nz_lo01 = 0;
#pragma unroll
    for (int wi = 0; wi < 4; ++wi)
#pragma unroll
        for (int bi = 0; bi < 4; ++bi) {
            unsigned int byte = (ww[wi] >> (bi * 8)) & 0xffu;
            if (byte && bi != 0) nz_hi = 1;
            if (byte && bi <= 1) nz_lo01 = 1;
        }
    int any_hi = __any(nz_hi);
    int any_lo01 = __any(nz_lo01);
    if (l == 0) *flag = (!any_hi) ? 1 : ((!any_lo01) ? 2 : 0);
}

__global__ void canon_mask_kernel(const void* __restrict__ m, const int* __restrict__ flag,
                                  unsigned char* __restrict__ out, int n) {
    int i = blockIdx.x * 256 + threadIdx.x;
    if (i >= n) return;
    int f = *flag;
    unsigned char v;
    if (f == 1)      v = (unsigned char)(((const int*)m)[i] != 0);
    else if (f == 2) v = (unsigned char)(((const float*)m)[i] != 0.0f);
    else             v = (unsigned char)(((const unsigned char*)m)[i] != 0);
    out[i] = v;
}

// ---------------------------------------------------------------------------
// fp32 -> bf16 elementwise (n4 = n/4)
__global__ void cvt_bf16_kernel(const float* __restrict__ in, unsigned short* __restrict__ out, int n4) {
    int i = blockIdx.x * 256 + threadIdx.x;
    if (i >= n4) return;
    float4 v = ((const float4*)in)[i];
    ushort4 o;
    o.x = f32_to_bf16(v.x); o.y = f32_to_bf16(v.y);
    o.z = f32_to_bf16(v.z); o.w = f32_to_bf16(v.w);
    ((ushort4*)out)[i] = o;
}

// ---------------------------------------------------------------------------
// W [4096][4096] fp32 -> WT [4096][4096] bf16 (WT[n][k] = W[k][n]); 64x64 tiles
__global__ __launch_bounds__(256) void transpose_w_kernel(const float* __restrict__ W,
                                                          unsigned short* __restrict__ WT) {
    __shared__ unsigned short lds[64][65];
    int bx = blockIdx.x & 63;    // n tile
    int by = blockIdx.x >> 6;    // k tile
    int t = threadIdx.x;
    int tr = t >> 4;             // 0..15
    int tc = (t & 15) * 4;       // 0..60
#pragma unroll
    for (int p = 0; p < 4; ++p) {
        int r = p * 16 + tr;
        float4 v = *(const float4*)(W + (size_t)(by * 64 + r) * D_ + bx * 64 + tc);
        lds[r][tc + 0] = f32_to_bf16(v.x);
        lds[r][tc + 1] = f32_to_bf16(v.y);
        lds[r][tc + 2] = f32_to_bf16(v.z);
        lds[r][tc + 3] = f32_to_bf16(v.w);
    }
    __syncthreads();
#pragma unroll
    for (int p = 0; p < 4; ++p) {
        int n = p * 16 + tr;
        ushort4 o;
        o.x = lds[tc + 0][n]; o.y = lds[tc + 1][n];
        o.z = lds[tc + 2][n]; o.w = lds[tc + 3][n];
        *(ushort4*)(WT + (size_t)(bx * 64 + n) * D_ + by * 64 + tc) = o;
    }
}

// ---------------------------------------------------------------------------
// V [M][H*DH] bf16 -> VT [B][H][DH][S] bf16. 64x64 tiles per (b,h,st,dt).
__global__ __launch_bounds__(256) void vt_kernel(const unsigned short* __restrict__ Vws,
                                                 unsigned short* __restrict__ Vtw) {
    __shared__ unsigned short lds[64][72];
    int bid = blockIdx.x;
    int dt = bid & 1;            // DH/64
    int st = (bid >> 1) & 15;    // S/64
    int h  = (bid >> 5) & 31;
    int b  = bid >> 10;
    int t = threadIdx.x;
    int r = t >> 2;              // 0..63
    int c0 = (t & 3) * 16;
    const unsigned short* src =
        Vws + (size_t)(b * S_ + st * 64 + r) * D_ + h * DH_ + dt * 64 + c0;
    bf16x8 v0 = *(const bf16x8*)(src);
    bf16x8 v1 = *(const bf16x8*)(src + 8);
    *(bf16x8*)&lds[r][c0] = v0;
    *(bf16x8*)&lds[r][c0 + 8] = v1;
    __syncthreads();
    // write: row dh = t>>2, s chunk (t&3)*16
    unsigned short tmp[16];
#pragma unroll
    for (int i = 0; i < 16; ++i) tmp[i] = lds[c0 + i][r];
    unsigned short* dst =
        Vtw + ((size_t)((b * H_ + h) * DH_ + dt * 64 + r)) * S_ + st * 64 + c0;
    *(bf16x8*)dst = *(bf16x8*)&tmp[0];
    *(bf16x8*)(dst + 8) = *(bf16x8*)&tmp[8];
}

// ---------------------------------------------------------------------------
// GEMM: C[M][N] = A[M][K] * BT[N][K]^T, bf16 inputs, fp32 accum.
// 128x128 tile, BK=64, 4 waves (2x2), 16x16x32 MFMA (m97 structure).
template <int OUT_BF16>
__global__ __launch_bounds__(256, 2) void gemm_kernel(const unsigned short* __restrict__ A,
                                                      const unsigned short* __restrict__ BT,
                                                      void* __restrict__ C, int M, int N, int K) {
    __shared__ unsigned short Atile[128 * 64];
    __shared__ unsigned short Btile[128 * 64];
    int bn_t = N >> 7;
    int bm = (int)blockIdx.x / bn_t;
    int bn = (int)blockIdx.x % bn_t;
    int m0 = bm << 7, n0 = bn << 7;
    int t = threadIdx.x, w = t >> 6, l = t & 63;
    int lr = l & 15, lg = l >> 4;
    int wm = (w >> 1) << 6, wn = (w & 1) << 6;

    f32x4 acc[4][4];
    f32x4 vzero = {0.f, 0.f, 0.f, 0.f};
#pragma unroll
    for (int i = 0; i < 4; ++i)
#pragma unroll
        for (int j = 0; j < 4; ++j) acc[i][j] = vzero;

    int srow = (w << 5) + (l >> 3);      // staging row (+ c*8)
    int scol = (l & 7) << 3;             // staging k-col
    const unsigned short* gA = A + (size_t)(m0 + srow) * K + scol;
    const unsigned short* gB = BT + (size_t)(n0 + srow) * K + scol;

    for (int kt = 0; kt < K; kt += 64) {
        __syncthreads();
#pragma unroll
        for (int c = 0; c < 4; ++c) {
            GLD16(gA + (size_t)(c * 8) * K + kt, &Atile[(((w << 2) + c)) << 9], l);
            GLD16(gB + (size_t)(c * 8) * K + kt, &Btile[(((w << 2) + c)) << 9], l);
        }
        __syncthreads();
#pragma unroll
        for (int kf = 0; kf < 2; ++kf) {
            bf16x8 af[4], bfr[4];
#pragma unroll
            for (int mi = 0; mi < 4; ++mi)
                af[mi] = *(const bf16x8*)&Atile[(wm + mi * 16 + lr) * 64 + kf * 32 + lg * 8];
#pragma unroll
            for (int ni = 0; ni < 4; ++ni)
                bfr[ni] = *(const bf16x8*)&Btile[(wn + ni * 16 + lr) * 64 + kf * 32 + lg * 8];
#pragma unroll
            for (int mi = 0; mi < 4; ++mi)
#pragma unroll
                for (int ni = 0; ni < 4; ++ni)
                    acc[mi][ni] = mfma16(af[mi], bfr[ni], acc[mi][ni]);
        }
    }
#pragma unroll
    for (int mi = 0; mi < 4; ++mi)
#pragma unroll
        for (int ni = 0; ni < 4; ++ni)
#pragma unroll
            for (int r = 0; r < 4; ++r) {
                int row = m0 + wm + mi * 16 + lg * 4 + r;
                int col = n0 + wn + ni * 16 + lr;
                if (OUT_BF16)
                    ((unsigned short*)C)[(size_t)row * N + col] = f32_to_bf16(acc[mi][ni][r]);
                else
                    ((float*)C)[(size_t)row * N + col] = acc[mi][ni][r];
            }
}

// ---------------------------------------------------------------------------
// Flash attention, pipelined. Grid: B*H*(S/64). Block: 256 thr (4 waves).
// K LDS [64][128] (chunk^=(row&7) swizzle), V LDS [128][64] (chunk^=(dh&7)),
// both double-buffered, staged via global_load_lds one tile ahead.
// Bias/mask prefetched to registers one tile ahead (double reg sets).
#define NEGF (-1e30f)
__global__ __launch_bounds__(256, 2) void attn_kernel(const unsigned short* __restrict__ Qw,
                                                      const unsigned short* __restrict__ Kw,
                                                      const unsigned short* __restrict__ Vtw,
                                                      const float* __restrict__ bias,
                                                      const unsigned char* __restrict__ maskc,
                                                      unsigned short* __restrict__ ctx) {
    __shared__ unsigned short Kbuf[2][64 * 128];
    __shared__ unsigned short Vbuf[2][128 * 64];
    __shared__ unsigned short Plds[4][16 * 72];

    int bid = blockIdx.x;
    int qt = bid & 15, h = (bid >> 4) & 31, b = bid >> 9;
    int t = threadIdx.x, w = t >> 6, l = t & 63;
    int lr = l & 15, lg = l >> 4;
    int q0 = (qt << 6) + (w << 4);

    // Q fragments
    bf16x8 qf[4];
    const unsigned short* Qp = Qw + ((size_t)(b * S_ + q0 + lr)) * D_ + h * DH_ + lg * 8;
#pragma unroll
    for (int kf = 0; kf < 4; ++kf) qf[kf] = *(const bf16x8*)(Qp + kf * 32);

    f32x4 o[8];
    f32x4 vzero = {0.f, 0.f, 0.f, 0.f};
#pragma unroll
    for (int i = 0; i < 8; ++i) o[i] = vzero;
    float m_run[4], l_run[4];
#pragma unroll
    for (int r = 0; r < 4; ++r) { m_run[r] = NEGF; l_run[r] = 0.f; }

    // per-lane bases: element (nb,r) of tile kt: +(r<<10) + kt*64 + nb*16
    const float* biasp = bias + (((size_t)(b * H_ + h)) << 20)
                              + (((size_t)(q0 + (lg << 2))) << 10) + lr;
    const unsigned char* mp = maskc + ((size_t)b << 20)
                              + (((size_t)(q0 + (lg << 2))) << 10) + lr;
    const unsigned short* Kg = Kw + (size_t)(b * S_) * D_ + h * DH_;
    const unsigned short* Vg = Vtw + (((size_t)(b * H_ + h)) * DH_) * S_;

    float br0[16], br1[16];
    int mr0[16], mr1[16];

#define STAGE_KV(KT, BUF)                                                          \
    do { int kv0_ = (KT) << 6;                                                     \
        _Pragma("unroll")                                                          \
        for (int c = 0; c < 4; ++c) {                                              \
            int seg = (w << 2) + c;                                                \
            int krow = (seg << 2) + (l >> 4);                                      \
            int kch = (l & 15) ^ (krow & 7);                                       \
            GLD16(Kg + (size_t)(kv0_ + krow) * D_ + (kch << 3),                    \
                  &Kbuf[BUF][seg << 9], l);                                        \
            int vrow = (seg << 3) + (l >> 3);                                      \
            int vch = (l & 7) ^ (vrow & 7);                                        \
            GLD16(Vg + (size_t)vrow * S_ + kv0_ + (vch << 3),                      \
                  &Vbuf[BUF][seg << 9], l);                                        \
        }                                                                          \
    } while (0)

#define LOAD_BM(BR, MR, KT)                                                        \
    do { int kv0_ = (KT) << 6;                                                     \
        _Pragma("unroll")                                                          \
        for (int nb = 0; nb < 4; ++nb)                                             \
            _Pragma("unroll")                                                      \
            for (int r = 0; r < 4; ++r) {                                          \
                BR[nb * 4 + r] = biasp[((size_t)r << 10) + kv0_ + (nb << 4)];      \
                MR[nb * 4 + r] = mp[((size_t)r << 10) + kv0_ + (nb << 4)];         \
            }                                                                      \
    } while (0)

#define COMPUTE(BUF, BR, MR)                                                       \
    do {                                                                           \
        f32x4 s_[4];                                                               \
        _Pragma("unroll")                                                          \
        for (int nb = 0; nb < 4; ++nb) {                                           \
            s_[nb] = vzero;                                                        \
            int krow = (nb << 4) + lr;                                             \
            _Pragma("unroll")                                                      \
            for (int kf = 0; kf < 4; ++kf) {                                       \
                int ba = ((krow << 8) + (((kf << 5) + (lg << 3)) << 1))            \
                         ^ ((krow & 7) << 4);                                      \
                bf16x8 kfr = *(const bf16x8*)((const char*)Kbuf[BUF] + ba);        \
                s_[nb] = mfma16(qf[kf], kfr, s_[nb]);                              \
            }                                                                      \
        }                                                                          \
        float sv[4][4];                                                            \
        _Pragma("unroll")                                                          \
        for (int nb = 0; nb < 4; ++nb)                                             \
            _Pragma("unroll")                                                      \
            for (int r = 0; r < 4; ++r) {                                          \
                float x = fmaf(s_[nb][r], 0.08838834764831845f, BR[nb * 4 + r]);   \
                sv[nb][r] = MR[nb * 4 + r] ? x : NEGF;                             \
            }                                                                      \
        float mt[4], al[4], rs[4];                                                 \
        _Pragma("unroll")                                                          \
        for (int r = 0; r < 4; ++r)                                                \
            mt[r] = fmaxf(fmaxf(sv[0][r], sv[1][r]), fmaxf(sv[2][r], sv[3][r]));   \
        _Pragma("unroll")                                                          \
        for (int off = 1; off < 16; off <<= 1)                                     \
            _Pragma("unroll")                                                      \
            for (int r = 0; r < 4; ++r) mt[r] = fmaxf(mt[r], __shfl_xor(mt[r], off, 64)); \
        _Pragma("unroll")                                                          \
        for (int r = 0; r < 4; ++r) {                                              \
            float mn = fmaxf(m_run[r], mt[r]);                                     \
            al[r] = __expf(m_run[r] - mn);                                         \
            m_run[r] = mn;                                                         \
        }                                                                          \
        _Pragma("unroll")                                                          \
        for (int nb = 0; nb < 4; ++nb)                                             \
            _Pragma("unroll")                                                      \
            for (int r = 0; r < 4; ++r) sv[nb][r] = __expf(sv[nb][r] - m_run[r]);  \
        _Pragma("unroll")                                                          \
        for (int r = 0; r < 4; ++r)                                                \
            rs[r] = (sv[0][r] + sv[1][r]) + (sv[2][r] + sv[3][r]);                 \
        _Pragma("unroll")                                                          \
        for (int off = 1; off < 16; off <<= 1)                                     \
            _Pragma("unroll")                                                      \
            for (int r = 0; r < 4; ++r) rs[r] += __shfl_xor(rs[r], off, 64);       \
        _Pragma("unroll")                                                          \
        for (int r = 0; r < 4; ++r) l_run[r] = l_run[r] * al[r] + rs[r];           \
        _Pragma("unroll")                                                          \
        for (int nb2 = 0; nb2 < 8; ++nb2) {                                        \
            o[nb2][0] *= al[0]; o[nb2][1] *= al[1];                                \
            o[nb2][2] *= al[2]; o[nb2][3] *= al[3];                                \
        }                                                                          \
        _Pragma("unroll")                                                          \
        for (int nb = 0; nb < 4; ++nb)                                             \
            _Pragma("unroll")                                                      \
            for (int r = 0; r < 4; ++r)                                            \
                Plds[w][((lg << 2) + r) * 72 + (nb << 4) + lr] = f32_to_bf16(sv[nb][r]); \
        _Pragma("unroll")                                                          \
        for (int kf2 = 0; kf2 < 2; ++kf2) {                                        \
            bf16x8 pf = *(const bf16x8*)&Plds[w][lr * 72 + (kf2 << 5) + (lg << 3)]; \
            _Pragma("unroll")                                                      \
            for (int nb2 = 0; nb2 < 8; ++nb2) {                                    \
                int dh = (nb2 << 4) + lr;                                          \
                int ba = ((dh << 7) + (((kf2 << 5) + (lg << 3)) << 1))             \
                         ^ ((dh & 7) << 4);                                        \
                bf16x8 vf = *(const bf16x8*)((const char*)Vbuf[BUF] + ba);         \
                o[nb2] = mfma16(pf, vf, o[nb2]);                                   \
            }                                                                      \
        }                                                                          \
    } while (0)

    // prologue: tile 0 in flight
    STAGE_KV(0, 0);
    LOAD_BM(br0, mr0, 0);

#pragma unroll 1
    for (int kt = 0; kt < 16; kt += 2) {
        __syncthreads();                       // buf0 (kt) + br0 ready (vmcnt drain)
        STAGE_KV(kt + 1, 1);                   // prefetch next tile into buf1
        LOAD_BM(br1, mr1, kt + 1);
        COMPUTE(0, br0, mr0);
        __syncthreads();                       // buf1 (kt+1) + br1 ready
        if (kt < 14) {
            STAGE_KV(kt + 2, 0);
            LOAD_BM(br0, mr0, kt + 2);
        }
        COMPUTE(1, br1, mr1);
    }

    // epilogue: normalize + store ctx bf16  [b*S+q][h*DH+dh]
#pragma unroll
    for (int r = 0; r < 4; ++r) {
        float inv = l_run[r] > 0.f ? 1.0f / l_run[r] : 0.f;
        int q = q0 + (lg << 2) + r;
        unsigned short* cp = ctx + ((size_t)(b * S_ + q)) * D_ + h * DH_ + lr;
#pragma unroll
        for (int nb2 = 0; nb2 < 8; ++nb2)
            cp[nb2 * 16] = f32_to_bf16(o[nb2][r] * inv);
    }
#undef STAGE_KV
#undef LOAD_BM
#undef COMPUTE
}

// ---------------------------------------------------------------------------
extern "C" void kernel_launch(void* const* d_in, const int* in_sizes, int n_in,
                              void* d_out, int out_size, void* d_ws, size_t ws_size,
                              hipStream_t stream) {
    const float* hq   = (const float*)d_in[0];
    const float* hkv  = (const float*)d_in[1];
    const void*  mask = d_in[2];
    const float* bias = (const float*)d_in[3];
    const float* Wq   = (const float*)d_in[4];
    const float* Wk   = (const float*)d_in[5];
    const float* Wv   = (const float*)d_in[6];
    const float* Wo   = (const float*)d_in[7];
    float* out = (float*)d_out;

    char* ws = (char*)d_ws;
    unsigned char* mask_c = (unsigned char*)ws;                    // 2 MB
    int* flag            = (int*)(ws + 2097152);                   // 256 B
    unsigned short* hq_b  = (unsigned short*)(ws + 2097408);       // 16 MB (reused as VT later)
    unsigned short* hkv_b = hq_b + 8388608;                        // 16 MB
    unsigned short* WT    = hkv_b + 8388608;                       // 32 MB
    unsigned short* Qws   = WT + 16777216;                         // 16 MB
    unsigned short* Kws   = Qws + 8388608;                         // 16 MB
    unsigned short* Vws   = Kws + 8388608;                         // 16 MB
    unsigned short* Cws   = Vws + 8388608;                         // 16 MB
    unsigned short* Vtw   = hq_b;   // hq_b is dead after the Q GEMM

    detect_mask_kernel<<<1, 64, 0, stream>>>((const unsigned char*)mask, flag);
    canon_mask_kernel<<<8192, 256, 0, stream>>>(mask, flag, mask_c, B_ * S_ * S_);
    cvt_bf16_kernel<<<8192, 256, 0, stream>>>(hq, hq_b, (B_ * S_ * D_) / 4);
    cvt_bf16_kernel<<<8192, 256, 0, stream>>>(hkv, hkv_b, (B_ * S_ * D_) / 4);

    transpose_w_kernel<<<4096, 256, 0, stream>>>(Wq, WT);
    gemm_kernel<1><<<(M_ / 128) * (D_ / 128), 256, 0, stream>>>(hq_b, WT, Qws, M_, D_, D_);
    transpose_w_kernel<<<4096, 256, 0, stream>>>(Wk, WT);
    gemm_kernel<1><<<(M_ / 128) * (D_ / 128), 256, 0, stream>>>(hkv_b, WT, Kws, M_, D_, D_);
    transpose_w_kernel<<<4096, 256, 0, stream>>>(Wv, WT);
    gemm_kernel<1><<<(M_ / 128) * (D_ / 128), 256, 0, stream>>>(hkv_b, WT, Vws, M_, D_, D_);

    vt_kernel<<<B_ * H_ * 16 * 2, 256, 0, stream>>>(Vws, Vtw);

    attn_kernel<<<B_ * H_ * (S_ / 64), 256, 0, stream>>>(Qws, Kws, Vtw, bias, mask_c, Cws);

    transpose_w_kernel<<<4096, 256, 0, stream>>>(Wo, WT);
    gemm_kernel<0><<<(M_ / 128) * (D_ / 128), 256, 0, stream>>>(Cws, WT, out, M_, D_, D_);
}

// Round 3
// 534.133 us; speedup vs baseline: 1.2337x; 1.1340x over previous
//
#include <hip/hip_runtime.h>
#include <stdint.h>

// ---------------------------------------------------------------------------
// CPMAntAttention: B=2,S=1024,D=4096,H=32,DH=128
// Round 3: deep-pipelined GEMM (128x256 tile, tri-buffer LDS, counted vmcnt,
// T2 swizzle, fused K+V GEMM N=8192), fused transposes/cvt. Attn unchanged.
// ---------------------------------------------------------------------------

#define B_  2
#define S_  1024
#define D_  4096
#define H_  32
#define DH_ 128
#define M_  (B_ * S_)          // 2048
#define KSTR 8192              // row stride of fused KV output

typedef __attribute__((ext_vector_type(8))) short bf16x8;
typedef __attribute__((ext_vector_type(4))) float f32x4;

static __device__ __forceinline__ unsigned short f32_to_bf16(float f) {
    unsigned int x = __float_as_uint(f);
    x += 0x7fffu + ((x >> 16) & 1u);   // RNE
    return (unsigned short)(x >> 16);
}

static __device__ __forceinline__ f32x4 mfma16(bf16x8 a, bf16x8 b, f32x4 c) {
    return __builtin_amdgcn_mfma_f32_16x16x32_bf16(a, b, c, 0, 0, 0);
}

#if defined(__has_builtin)
#if __has_builtin(__builtin_amdgcn_global_load_lds)
#define HAVE_GLOAD_LDS 1
#endif
#endif

#ifdef HAVE_GLOAD_LDS
#define GLD16(g, lbase, lane)                                                  \
    __builtin_amdgcn_global_load_lds(                                          \
        (const __attribute__((address_space(1))) void*)(g),                    \
        (__attribute__((address_space(3))) void*)(lbase), 16, 0, 0)
#else
#define GLD16(g, lbase, lane)                                                  \
    do { *(bf16x8*)((unsigned short*)(lbase) + (size_t)(lane) * 8) =           \
             *(const bf16x8*)(g); } while (0)
#endif

// ---------------------------------------------------------------------------
// mask dtype detection: 0 = u8/bool, 1 = int32, 2 = float32. 64 lanes.
__global__ void detect_mask_kernel(const unsigned char* __restrict__ m, int* flag) {
    int l = threadIdx.x;
    uint4 v = ((const uint4*)m)[l];
    unsigned int ww[4] = {v.x, v.y, v.z, v.w};
    int nz_hi = 0, nz_lo01 = 0;
#pragma unroll
    for (int wi = 0; wi < 4; ++wi)
#pragma unroll
        for (int bi = 0; bi < 4; ++bi) {
            unsigned int byte = (ww[wi] >> (bi * 8)) & 0xffu;
            if (byte && bi != 0) nz_hi = 1;
            if (byte && bi <= 1) nz_lo01 = 1;
        }
    int any_hi = __any(nz_hi);
    int any_lo01 = __any(nz_lo01);
    if (l == 0) *flag = (!any_hi) ? 1 : ((!any_lo01) ? 2 : 0);
}

__global__ void canon_mask_kernel(const void* __restrict__ m, const int* __restrict__ flag,
                                  unsigned char* __restrict__ out, int n) {
    int i = blockIdx.x * 256 + threadIdx.x;
    if (i >= n) return;
    int f = *flag;
    unsigned char v;
    if (f == 1)      v = (unsigned char)(((const int*)m)[i] != 0);
    else if (f == 2) v = (unsigned char)(((const float*)m)[i] != 0.0f);
    else             v = (unsigned char)(((const unsigned char*)m)[i] != 0);
    out[i] = v;
}

// ---------------------------------------------------------------------------
// fp32 -> bf16 for both hidden tensors in one launch. n4 = 2M float4 each.
__global__ void cvt2_bf16_kernel(const float* __restrict__ a, const float* __restrict__ b,
                                 unsigned short* __restrict__ oa, unsigned short* __restrict__ ob) {
    int i = blockIdx.x * 256 + threadIdx.x;          // 0 .. 4M-1
    const int n4 = (B_ * S_ * D_) / 4;               // 2M
    const float* src = (i < n4) ? a : b;
    unsigned short* dst = (i < n4) ? oa : ob;
    int j = (i < n4) ? i : i - n4;
    float4 v = ((const float4*)src)[j];
    ushort4 o;
    o.x = f32_to_bf16(v.x); o.y = f32_to_bf16(v.y);
    o.z = f32_to_bf16(v.z); o.w = f32_to_bf16(v.w);
    ((ushort4*)dst)[j] = o;
}

// ---------------------------------------------------------------------------
// All 4 weight transposes in one launch. W [4096][4096] f32 -> WT [n][k] bf16.
__global__ __launch_bounds__(256) void transpose_all_kernel(
        const float* __restrict__ Wq, const float* __restrict__ Wk,
        const float* __restrict__ Wv, const float* __restrict__ Wo,
        unsigned short* __restrict__ WTq, unsigned short* __restrict__ WTkv,
        unsigned short* __restrict__ WTo) {
    __shared__ unsigned short lds[64][65];
    int which = blockIdx.x >> 12;
    int bid = blockIdx.x & 4095;
    const float* W = (which == 0) ? Wq : (which == 1) ? Wk : (which == 2) ? Wv : Wo;
    unsigned short* WT = (which == 0) ? WTq
                       : (which == 1) ? WTkv
                       : (which == 2) ? (WTkv + (size_t)4096 * 4096)
                                      : WTo;
    int bx = bid & 63;    // n tile
    int by = bid >> 6;    // k tile
    int t = threadIdx.x;
    int tr = t >> 4;
    int tc = (t & 15) * 4;
#pragma unroll
    for (int p = 0; p < 4; ++p) {
        int r = p * 16 + tr;
        float4 v = *(const float4*)(W + (size_t)(by * 64 + r) * D_ + bx * 64 + tc);
        lds[r][tc + 0] = f32_to_bf16(v.x);
        lds[r][tc + 1] = f32_to_bf16(v.y);
        lds[r][tc + 2] = f32_to_bf16(v.z);
        lds[r][tc + 3] = f32_to_bf16(v.w);
    }
    __syncthreads();
#pragma unroll
    for (int p = 0; p < 4; ++p) {
        int n = p * 16 + tr;
        ushort4 o;
        o.x = lds[tc + 0][n]; o.y = lds[tc + 1][n];
        o.z = lds[tc + 2][n]; o.w = lds[tc + 3][n];
        *(ushort4*)(WT + (size_t)(bx * 64 + n) * D_ + by * 64 + tc) = o;
    }
}

// ---------------------------------------------------------------------------
// V slice of fused KV [M][8192] -> VT [B][H][DH][S] bf16.
__global__ __launch_bounds__(256) void vt_kernel(const unsigned short* __restrict__ KV,
                                                 unsigned short* __restrict__ Vtw) {
    __shared__ unsigned short lds[64][72];
    int bid = blockIdx.x;
    int dt = bid & 1;            // DH/64
    int st = (bid >> 1) & 15;    // S/64
    int h  = (bid >> 5) & 31;
    int b  = bid >> 10;
    int t = threadIdx.x;
    int r = t >> 2;
    int c0 = (t & 3) * 16;
    const unsigned short* src =
        KV + (size_t)(b * S_ + st * 64 + r) * KSTR + 4096 + h * DH_ + dt * 64 + c0;
    bf16x8 v0 = *(const bf16x8*)(src);
    bf16x8 v1 = *(const bf16x8*)(src + 8);
    *(bf16x8*)&lds[r][c0] = v0;
    *(bf16x8*)&lds[r][c0 + 8] = v1;
    __syncthreads();
    unsigned short tmp[16];
#pragma unroll
    for (int i = 0; i < 16; ++i) tmp[i] = lds[c0 + i][r];
    unsigned short* dst =
        Vtw + ((size_t)((b * H_ + h) * DH_ + dt * 64 + r)) * S_ + st * 64 + c0;
    *(bf16x8*)dst = *(bf16x8*)&tmp[0];
    *(bf16x8*)(dst + 8) = *(bf16x8*)&tmp[8];
}

// ---------------------------------------------------------------------------
// Deep-pipelined GEMM: C[M][N] = A[M][K] * BT[N][K]^T, bf16 in, fp32 accum.
// BM=128, BN=256, BK=64, 512 thr (8 waves, 2M x 4N, 64x64 per wave).
// Tri-buffered LDS (3 x 48KB), prefetch distance 2, counted vmcnt(12),
// raw s_barrier (no vmcnt(0) drain), XOR-swizzled LDS (via pre-swizzled src).
template <int OUT_BF16>
__global__ __launch_bounds__(512, 2) void gemm8p_kernel(const unsigned short* __restrict__ A,
                                                        const unsigned short* __restrict__ BT,
                                                        void* __restrict__ C,
                                                        int M, int N, int K) {
    // per buffer: A 128x64 bf16 = 16KB (8192 us), B 256x64 = 32KB (16384 us)
    __shared__ unsigned short lds[3][24576];   // 147456 B total
    char* ldsc = (char*)&lds[0][0];

    int nbn = N >> 8;
    int bm = (int)blockIdx.x / nbn;
    int bn = (int)blockIdx.x % nbn;
    int m0 = bm << 7, n0 = bn << 8;
    int t = threadIdx.x, w = t >> 6, l = t & 63;
    int lr = l & 15, lg = l >> 4;
    int wm = (w >> 2) << 6;      // 0 / 64
    int wn = (w & 3) << 6;       // 0 / 64 / 128 / 192

    f32x4 acc[2][4];             // [mi pair slot unused]; see below: use 4x4
    // full 4m x 4n accumulator
    f32x4 ac[4][4];
    f32x4 vzero = {0.f, 0.f, 0.f, 0.f};
#pragma unroll
    for (int i = 0; i < 4; ++i)
#pragma unroll
        for (int j = 0; j < 4; ++j) ac[i][j] = vzero;
    (void)acc;

    // staging: 48 segs of 64 chunks(16B); seg = w*6+i. seg<16 -> A, else B.
    // chunk c within region: row = seg'*8 + (l>>3), ch = l&7, swizzled ch = (l&7)^(l>>3)
    int sch = (l & 7) ^ (l >> 3);
    int subrow = l >> 3;

#define STAGE(KT, BUF)                                                         \
    do { int koff_ = (KT) << 6;                                                \
        _Pragma("unroll")                                                      \
        for (int i = 0; i < 6; ++i) {                                          \
            int seg = w * 6 + i;                                               \
            char* dst = ldsc + (size_t)(BUF) * 49152 + (size_t)seg * 1024;     \
            if (seg < 16) {                                                    \
                int row = m0 + seg * 8 + subrow;                               \
                GLD16(A + (size_t)row * K + koff_ + (sch << 3), dst, l);       \
            } else {                                                           \
                int row = n0 + (seg - 16) * 8 + subrow;                        \
                GLD16(BT + (size_t)row * K + koff_ + (sch << 3), dst, l);      \
            }                                                                  \
        }                                                                      \
    } while (0)

    const int NT = K >> 6;       // 64
    STAGE(0, 0);
    STAGE(1, 1);

    int cur = 0;                 // buffer holding tile kt
    int pre = 2;                 // buffer receiving tile kt+2
#pragma unroll 1
    for (int kt = 0; kt < NT; ++kt) {
        asm volatile("s_waitcnt lgkmcnt(0)" ::: "memory");
        __builtin_amdgcn_s_barrier();          // all waves done reading buf 'pre'
        if (kt + 2 < NT) {
            STAGE(kt + 2, pre);
            asm volatile("s_waitcnt vmcnt(12)" ::: "memory");
        } else if (kt + 1 < NT) {
            asm volatile("s_waitcnt vmcnt(6)" ::: "memory");
        } else {
            asm volatile("s_waitcnt vmcnt(0)" ::: "memory");
        }
        __builtin_amdgcn_s_barrier();          // tile kt fully in LDS

        const char* Ab = ldsc + (size_t)cur * 49152;
        const char* Bb = Ab + 16384;

        bf16x8 bfr[4][2], af0[2][2], af1[2][2];
#pragma unroll
        for (int ni = 0; ni < 4; ++ni)
#pragma unroll
            for (int kk = 0; kk < 2; ++kk) {
                int row = wn + ni * 16 + lr;
                bfr[ni][kk] = *(const bf16x8*)(Bb + row * 128 +
                                ((((kk << 2) + lg) ^ (row & 7)) << 4));
            }
#pragma unroll
        for (int mi = 0; mi < 2; ++mi)
#pragma unroll
            for (int kk = 0; kk < 2; ++kk) {
                int row = wm + mi * 16 + lr;
                af0[mi][kk] = *(const bf16x8*)(Ab + row * 128 +
                                ((((kk << 2) + lg) ^ (row & 7)) << 4));
            }
        __builtin_amdgcn_s_setprio(1);
#pragma unroll
        for (int mi = 0; mi < 2; ++mi)
#pragma unroll
            for (int ni = 0; ni < 4; ++ni)
#pragma unroll
                for (int kk = 0; kk < 2; ++kk)
                    ac[mi][ni] = mfma16(af0[mi][kk], bfr[ni][kk], ac[mi][ni]);
        __builtin_amdgcn_s_setprio(0);
#pragma unroll
        for (int mi = 0; mi < 2; ++mi)
#pragma unroll
            for (int kk = 0; kk < 2; ++kk) {
                int row = wm + (mi + 2) * 16 + lr;
                af1[mi][kk] = *(const bf16x8*)(Ab + row * 128 +
                                ((((kk << 2) + lg) ^ (row & 7)) << 4));
            }
        __builtin_amdgcn_s_setprio(1);
#pragma unroll
        for (int mi = 0; mi < 2; ++mi)
#pragma unroll
            for (int ni = 0; ni < 4; ++ni)
#pragma unroll
                for (int kk = 0; kk < 2; ++kk)
                    ac[mi + 2][ni] = mfma16(af1[mi][kk], bfr[ni][kk], ac[mi + 2][ni]);
        __builtin_amdgcn_s_setprio(0);

        cur = (cur == 2) ? 0 : cur + 1;
        pre = (pre == 2) ? 0 : pre + 1;
    }
#undef STAGE

    // epilogue
#pragma unroll
    for (int mi = 0; mi < 4; ++mi)
#pragma unroll
        for (int ni = 0; ni < 4; ++ni)
#pragma unroll
            for (int r = 0; r < 4; ++r) {
                int row = m0 + wm + mi * 16 + lg * 4 + r;
                int col = n0 + wn + ni * 16 + lr;
                if (OUT_BF16)
                    ((unsigned short*)C)[(size_t)row * N + col] = f32_to_bf16(ac[mi][ni][r]);
                else
                    ((float*)C)[(size_t)row * N + col] = ac[mi][ni][r];
            }
}

// ---------------------------------------------------------------------------
// Flash attention (round-2 structure; K read from fused KV buffer, stride 8192)
#define NEGF (-1e30f)
__global__ __launch_bounds__(256, 2) void attn_kernel(const unsigned short* __restrict__ Qw,
                                                      const unsigned short* __restrict__ KV,
                                                      const unsigned short* __restrict__ Vtw,
                                                      const float* __restrict__ bias,
                                                      const unsigned char* __restrict__ maskc,
                                                      unsigned short* __restrict__ ctx) {
    __shared__ unsigned short Kbuf[2][64 * 128];
    __shared__ unsigned short Vbuf[2][128 * 64];
    __shared__ unsigned short Plds[4][16 * 72];

    int bid = blockIdx.x;
    int qt = bid & 15, h = (bid >> 4) & 31, b = bid >> 9;
    int t = threadIdx.x, w = t >> 6, l = t & 63;
    int lr = l & 15, lg = l >> 4;
    int q0 = (qt << 6) + (w << 4);

    bf16x8 qf[4];
    const unsigned short* Qp = Qw + ((size_t)(b * S_ + q0 + lr)) * D_ + h * DH_ + lg * 8;
#pragma unroll
    for (int kf = 0; kf < 4; ++kf) qf[kf] = *(const bf16x8*)(Qp + kf * 32);

    f32x4 o[8];
    f32x4 vzero = {0.f, 0.f, 0.f, 0.f};
#pragma unroll
    for (int i = 0; i < 8; ++i) o[i] = vzero;
    float m_run[4], l_run[4];
#pragma unroll
    for (int r = 0; r < 4; ++r) { m_run[r] = NEGF; l_run[r] = 0.f; }

    const float* biasp = bias + (((size_t)(b * H_ + h)) << 20)
                              + (((size_t)(q0 + (lg << 2))) << 10) + lr;
    const unsigned char* mp = maskc + ((size_t)b << 20)
                              + (((size_t)(q0 + (lg << 2))) << 10) + lr;
    const unsigned short* Kg = KV + (size_t)(b * S_) * KSTR + h * DH_;
    const unsigned short* Vg = Vtw + (((size_t)(b * H_ + h)) * DH_) * S_;

    float br0[16], br1[16];
    int mr0[16], mr1[16];

#define STAGE_KV(KT, BUF)                                                          \
    do { int kv0_ = (KT) << 6;                                                     \
        _Pragma("unroll")                                                          \
        for (int c = 0; c < 4; ++c) {                                              \
            int seg = (w << 2) + c;                                                \
            int krow = (seg << 2) + (l >> 4);                                      \
            int kch = (l & 15) ^ (krow & 7);                                       \
            GLD16(Kg + (size_t)(kv0_ + krow) * KSTR + (kch << 3),                  \
                  &Kbuf[BUF][seg << 9], l);                                        \
            int vrow = (seg << 3) + (l >> 3);                                      \
            int vch = (l & 7) ^ (vrow & 7);                                        \
            GLD16(Vg + (size_t)vrow * S_ + kv0_ + (vch << 3),                      \
                  &Vbuf[BUF][seg << 9], l);                                        \
        }                                                                          \
    } while (0)

#define LOAD_BM(BR, MR, KT)                                                        \
    do { int kv0_ = (KT) << 6;                                                     \
        _Pragma("unroll")                                                          \
        for (int nb = 0; nb < 4; ++nb)                                             \
            _Pragma("unroll")                                                      \
            for (int r = 0; r < 4; ++r) {                                          \
                BR[nb * 4 + r] = biasp[((size_t)r << 10) + kv0_ + (nb << 4)];      \
                MR[nb * 4 + r] = mp[((size_t)r << 10) + kv0_ + (nb << 4)];         \
            }                                                                      \
    } while (0)

#define COMPUTE(BUF, BR, MR)                                                       \
    do {                                                                           \
        f32x4 s_[4];                                                               \
        _Pragma("unroll")                                                          \
        for (int nb = 0; nb < 4; ++nb) {                                           \
            s_[nb] = vzero;                                                        \
            int krow = (nb << 4) + lr;                                             \
            _Pragma("unroll")                                                      \
            for (int kf = 0; kf < 4; ++kf) {                                       \
                int ba = ((krow << 8) + (((kf << 5) + (lg << 3)) << 1))            \
                         ^ ((krow & 7) << 4);                                      \
                bf16x8 kfr = *(const bf16x8*)((const char*)Kbuf[BUF] + ba);        \
                s_[nb] = mfma16(qf[kf], kfr, s_[nb]);                              \
            }                                                                      \
        }                                                                          \
        float sv[4][4];                                                            \
        _Pragma("unroll")                                                          \
        for (int nb = 0; nb < 4; ++nb)                                             \
            _Pragma("unroll")                                                      \
            for (int r = 0; r < 4; ++r) {                                          \
                float x = fmaf(s_[nb][r], 0.08838834764831845f, BR[nb * 4 + r]);   \
                sv[nb][r] = MR[nb * 4 + r] ? x : NEGF;                             \
            }                                                                      \
        float mt[4], al[4], rs[4];                                                 \
        _Pragma("unroll")                                                          \
        for (int r = 0; r < 4; ++r)                                                \
            mt[r] = fmaxf(fmaxf(sv[0][r], sv[1][r]), fmaxf(sv[2][r], sv[3][r]));   \
        _Pragma("unroll")                                                          \
        for (int off = 1; off < 16; off <<= 1)                                     \
            _Pragma("unroll")                                                      \
            for (int r = 0; r < 4; ++r) mt[r] = fmaxf(mt[r], __shfl_xor(mt[r], off, 64)); \
        _Pragma("unroll")                                                          \
        for (int r = 0; r < 4; ++r) {                                              \
            float mn = fmaxf(m_run[r], mt[r]);                                     \
            al[r] = __expf(m_run[r] - mn);                                         \
            m_run[r] = mn;                                                         \
        }                                                                          \
        _Pragma("unroll")                                                          \
        for (int nb = 0; nb < 4; ++nb)                                             \
            _Pragma("unroll")                                                      \
            for (int r = 0; r < 4; ++r) sv[nb][r] = __expf(sv[nb][r] - m_run[r]);  \
        _Pragma("unroll")                                                          \
        for (int r = 0; r < 4; ++r)                                                \
            rs[r] = (sv[0][r] + sv[1][r]) + (sv[2][r] + sv[3][r]);                 \
        _Pragma("unroll")                                                          \
        for (int off = 1; off < 16; off <<= 1)                                     \
            _Pragma("unroll")                                                      \
            for (int r = 0; r < 4; ++r) rs[r] += __shfl_xor(rs[r], off, 64);       \
        _Pragma("unroll")                                                          \
        for (int r = 0; r < 4; ++r) l_run[r] = l_run[r] * al[r] + rs[r];           \
        _Pragma("unroll")                                                          \
        for (int nb2 = 0; nb2 < 8; ++nb2) {                                        \
            o[nb2][0] *= al[0]; o[nb2][1] *= al[1];                                \
            o[nb2][2] *= al[2]; o[nb2][3] *= al[3];                                \
        }                                                                          \
        _Pragma("unroll")                                                          \
        for (int nb = 0; nb < 4; ++nb)                                             \
            _Pragma("unroll")                                                      \
            for (int r = 0; r < 4; ++r)                                            \
                Plds[w][((lg << 2) + r) * 72 + (nb << 4) + lr] = f32_to_bf16(sv[nb][r]); \
        _Pragma("unroll")                                                          \
        for (int kf2 = 0; kf2 < 2; ++kf2) {                                        \
            bf16x8 pf = *(const bf16x8*)&Plds[w][lr * 72 + (kf2 << 5) + (lg << 3)]; \
            _Pragma("unroll")                                                      \
            for (int nb2 = 0; nb2 < 8; ++nb2) {                                    \
                int dh = (nb2 << 4) + lr;                                          \
                int ba = ((dh << 7) + (((kf2 << 5) + (lg << 3)) << 1))             \
                         ^ ((dh & 7) << 4);                                        \
                bf16x8 vf = *(const bf16x8*)((const char*)Vbuf[BUF] + ba);         \
                o[nb2] = mfma16(pf, vf, o[nb2]);                                   \
            }                                                                      \
        }                                                                          \
    } while (0)

    STAGE_KV(0, 0);
    LOAD_BM(br0, mr0, 0);

#pragma unroll 1
    for (int kt = 0; kt < 16; kt += 2) {
        __syncthreads();
        STAGE_KV(kt + 1, 1);
        LOAD_BM(br1, mr1, kt + 1);
        COMPUTE(0, br0, mr0);
        __syncthreads();
        if (kt < 14) {
            STAGE_KV(kt + 2, 0);
            LOAD_BM(br0, mr0, kt + 2);
        }
        COMPUTE(1, br1, mr1);
    }

#pragma unroll
    for (int r = 0; r < 4; ++r) {
        float inv = l_run[r] > 0.f ? 1.0f / l_run[r] : 0.f;
        int q = q0 + (lg << 2) + r;
        unsigned short* cp = ctx + ((size_t)(b * S_ + q)) * D_ + h * DH_ + lr;
#pragma unroll
        for (int nb2 = 0; nb2 < 8; ++nb2)
            cp[nb2 * 16] = f32_to_bf16(o[nb2][r] * inv);
    }
#undef STAGE_KV
#undef LOAD_BM
#undef COMPUTE
}

// ---------------------------------------------------------------------------
extern "C" void kernel_launch(void* const* d_in, const int* in_sizes, int n_in,
                              void* d_out, int out_size, void* d_ws, size_t ws_size,
                              hipStream_t stream) {
    const float* hq   = (const float*)d_in[0];
    const float* hkv  = (const float*)d_in[1];
    const void*  mask = d_in[2];
    const float* bias = (const float*)d_in[3];
    const float* Wq   = (const float*)d_in[4];
    const float* Wk   = (const float*)d_in[5];
    const float* Wv   = (const float*)d_in[6];
    const float* Wo   = (const float*)d_in[7];
    float* out = (float*)d_out;

    char* ws = (char*)d_ws;
    unsigned char* mask_c = (unsigned char*)ws;                        // 2 MB
    int* flag             = (int*)(ws + (2u << 20));
    unsigned short* hq_b  = (unsigned short*)(ws + (2u << 20) + 4096); // 16 MB
    unsigned short* hkv_b = hq_b + ((size_t)1 << 23);                  // 16 MB
    unsigned short* WTq   = hkv_b + ((size_t)1 << 23);                 // 32 MB
    unsigned short* WTo   = WTq + ((size_t)1 << 24);                   // 32 MB
    unsigned short* WTkv  = WTo + ((size_t)1 << 24);                   // 64 MB
    unsigned short* Qws   = WTkv + ((size_t)1 << 25);                  // 16 MB
    unsigned short* KVws  = Qws + ((size_t)1 << 23);                   // 32 MB
    unsigned short* Cws   = KVws + ((size_t)1 << 24);                  // 16 MB
    unsigned short* Vtw   = Cws + ((size_t)1 << 23);                   // 16 MB

    detect_mask_kernel<<<1, 64, 0, stream>>>((const unsigned char*)mask, flag);
    canon_mask_kernel<<<8192, 256, 0, stream>>>(mask, flag, mask_c, B_ * S_ * S_);
    cvt2_bf16_kernel<<<16384, 256, 0, stream>>>(hq, hkv, hq_b, hkv_b);
    transpose_all_kernel<<<16384, 256, 0, stream>>>(Wq, Wk, Wv, Wo, WTq, WTkv, WTo);

    // Q = hq_b @ WqT   (M=2048, N=4096) : 256 blocks
    gemm8p_kernel<1><<<(M_ / 128) * (D_ / 256), 512, 0, stream>>>(hq_b, WTq, Qws, M_, D_, D_);
    // [K|V] = hkv_b @ [WkT;WvT]  (N=8192) : 512 blocks
    gemm8p_kernel<1><<<(M_ / 128) * (2 * D_ / 256), 512, 0, stream>>>(hkv_b, WTkv, KVws, M_, 2 * D_, D_);

    vt_kernel<<<B_ * H_ * 16 * 2, 256, 0, stream>>>(KVws, Vtw);
    attn_kernel<<<B_ * H_ * (S_ / 64), 256, 0, stream>>>(Qws, KVws, Vtw, bias, mask_c, Cws);

    // out = Cws @ WoT  (fp32 out) : 256 blocks
    gemm8p_kernel<0><<<(M_ / 128) * (D_ / 256), 512, 0, stream>>>(Cws, WTo, out, M_, D_, D_);
}

// Round 6
// 526.317 us; speedup vs baseline: 1.2520x; 1.0148x over previous
//
#include <hip/hip_runtime.h>
#include <stdint.h>

// ---------------------------------------------------------------------------
// CPMAntAttention: B=2,S=1024,D=4096,H=32,DH=128
// Round 6: fix r5's tail race — last elem (B1 of final K-tile) is issued at
// tile NT-2 phase 2 with nothing after it, so vmcnt(2) at tile NT-1 never
// certified it. Final tile now drains vmcnt(0). Schedule otherwise identical:
// phase-pipelined 256x256 GEMM (9-slot half-tile stream, vmcnt(2)/tile,
// 4 barriers/tile, setprio MFMA clusters); Q fused into KV launch; O split-K2.
// ---------------------------------------------------------------------------

#define B_  2
#define S_  1024
#define D_  4096
#define H_  32
#define DH_ 128
#define M_  (B_ * S_)          // 2048
#define KSTR 8192              // row stride of fused KV output

typedef __attribute__((ext_vector_type(8))) short bf16x8;
typedef __attribute__((ext_vector_type(4))) float f32x4;

static __device__ __forceinline__ unsigned short f32_to_bf16(float f) {
    unsigned int x = __float_as_uint(f);
    x += 0x7fffu + ((x >> 16) & 1u);   // RNE
    return (unsigned short)(x >> 16);
}

static __device__ __forceinline__ f32x4 mfma16(bf16x8 a, bf16x8 b, f32x4 c) {
    return __builtin_amdgcn_mfma_f32_16x16x32_bf16(a, b, c, 0, 0, 0);
}

#if defined(__has_builtin)
#if __has_builtin(__builtin_amdgcn_global_load_lds)
#define HAVE_GLOAD_LDS 1
#endif
#endif

#ifdef HAVE_GLOAD_LDS
#define GLD16(g, lbase, lane)                                                  \
    __builtin_amdgcn_global_load_lds(                                          \
        (const __attribute__((address_space(1))) void*)(g),                    \
        (__attribute__((address_space(3))) void*)(lbase), 16, 0, 0)
#else
#define GLD16(g, lbase, lane)                                                  \
    do { *(bf16x8*)((unsigned short*)(lbase) + (size_t)(lane) * 8) =           \
             *(const bf16x8*)(g); } while (0)
#endif

// ---------------------------------------------------------------------------
__global__ void detect_mask_kernel(const unsigned char* __restrict__ m, int* flag) {
    int l = threadIdx.x;
    uint4 v = ((const uint4*)m)[l];
    unsigned int ww[4] = {v.x, v.y, v.z, v.w};
    int nz_hi = 0, nz_lo01 = 0;
#pragma unroll
    for (int wi = 0; wi < 4; ++wi)
#pragma unroll
        for (int bi = 0; bi < 4; ++bi) {
            unsigned int byte = (ww[wi] >> (bi * 8)) & 0xffu;
            if (byte && bi != 0) nz_hi = 1;
            if (byte && bi <= 1) nz_lo01 = 1;
        }
    int any_hi = __any(nz_hi);
    int any_lo01 = __any(nz_lo01);
    if (l == 0) *flag = (!any_hi) ? 1 : ((!any_lo01) ? 2 : 0);
}

__global__ void canon_mask_kernel(const void* __restrict__ m, const int* __restrict__ flag,
                                  unsigned char* __restrict__ out, int n) {
    int i = blockIdx.x * 256 + threadIdx.x;
    if (i >= n) return;
    int f = *flag;
    unsigned char v;
    if (f == 1)      v = (unsigned char)(((const int*)m)[i] != 0);
    else if (f == 2) v = (unsigned char)(((const float*)m)[i] != 0.0f);
    else             v = (unsigned char)(((const unsigned char*)m)[i] != 0);
    out[i] = v;
}

__global__ void cvt2_bf16_kernel(const float* __restrict__ a, const float* __restrict__ b,
                                 unsigned short* __restrict__ oa, unsigned short* __restrict__ ob) {
    int i = blockIdx.x * 256 + threadIdx.x;
    const int n4 = (B_ * S_ * D_) / 4;
    const float* src = (i < n4) ? a : b;
    unsigned short* dst = (i < n4) ? oa : ob;
    int j = (i < n4) ? i : i - n4;
    float4 v = ((const float4*)src)[j];
    ushort4 o;
    o.x = f32_to_bf16(v.x); o.y = f32_to_bf16(v.y);
    o.z = f32_to_bf16(v.z); o.w = f32_to_bf16(v.w);
    ((ushort4*)dst)[j] = o;
}

__global__ __launch_bounds__(256) void transpose_all_kernel(
        const float* __restrict__ Wq, const float* __restrict__ Wk,
        const float* __restrict__ Wv, const float* __restrict__ Wo,
        unsigned short* __restrict__ WTq, unsigned short* __restrict__ WTkv,
        unsigned short* __restrict__ WTo) {
    __shared__ unsigned short lds[64][65];
    int which = blockIdx.x >> 12;
    int bid = blockIdx.x & 4095;
    const float* W = (which == 0) ? Wq : (which == 1) ? Wk : (which == 2) ? Wv : Wo;
    unsigned short* WT = (which == 0) ? WTq
                       : (which == 1) ? WTkv
                       : (which == 2) ? (WTkv + (size_t)4096 * 4096)
                                      : WTo;
    int bx = bid & 63;
    int by = bid >> 6;
    int t = threadIdx.x;
    int tr = t >> 4;
    int tc = (t & 15) * 4;
#pragma unroll
    for (int p = 0; p < 4; ++p) {
        int r = p * 16 + tr;
        float4 v = *(const float4*)(W + (size_t)(by * 64 + r) * D_ + bx * 64 + tc);
        lds[r][tc + 0] = f32_to_bf16(v.x);
        lds[r][tc + 1] = f32_to_bf16(v.y);
        lds[r][tc + 2] = f32_to_bf16(v.z);
        lds[r][tc + 3] = f32_to_bf16(v.w);
    }
    __syncthreads();
#pragma unroll
    for (int p = 0; p < 4; ++p) {
        int n = p * 16 + tr;
        ushort4 o;
        o.x = lds[tc + 0][n]; o.y = lds[tc + 1][n];
        o.z = lds[tc + 2][n]; o.w = lds[tc + 3][n];
        *(ushort4*)(WT + (size_t)(bx * 64 + n) * D_ + by * 64 + tc) = o;
    }
}

__global__ __launch_bounds__(256) void vt_kernel(const unsigned short* __restrict__ KV,
                                                 unsigned short* __restrict__ Vtw) {
    __shared__ unsigned short lds[64][72];
    int bid = blockIdx.x;
    int dt = bid & 1;
    int st = (bid >> 1) & 15;
    int h  = (bid >> 5) & 31;
    int b  = bid >> 10;
    int t = threadIdx.x;
    int r = t >> 2;
    int c0 = (t & 3) * 16;
    const unsigned short* src =
        KV + (size_t)(b * S_ + st * 64 + r) * KSTR + 4096 + h * DH_ + dt * 64 + c0;
    bf16x8 v0 = *(const bf16x8*)(src);
    bf16x8 v1 = *(const bf16x8*)(src + 8);
    *(bf16x8*)&lds[r][c0] = v0;
    *(bf16x8*)&lds[r][c0 + 8] = v1;
    __syncthreads();
    unsigned short tmp[16];
#pragma unroll
    for (int i = 0; i < 16; ++i) tmp[i] = lds[c0 + i][r];
    unsigned short* dst =
        Vtw + ((size_t)((b * H_ + h) * DH_ + dt * 64 + r)) * S_ + st * 64 + c0;
    *(bf16x8*)dst = *(bf16x8*)&tmp[0];
    *(bf16x8*)(dst + 8) = *(bf16x8*)&tmp[8];
}

// ---------------------------------------------------------------------------
// Phase-pipelined GEMM core. Tile 256x256, BK=64, 512 thr (8 waves 2Mx4N),
// per-wave output 128x64 (8 m-frags x 4 n-frags). K-tile = 4 half-tiles
// (A0,A1,B0,B1: elem er=0..3), streamed through 9 LDS slots of 16KB.
// Phase P=4*tau+r: MFMA quadrant r (m-frags 2r,2r+1 x all nf x kk) + stage
// half-tile elem P+5 into slot (P+5)%9. vmcnt(2) once per tile at r==0,
// EXCEPT the final tile which drains vmcnt(0): the last elem 4NT-1 is issued
// at tile NT-2 phase 2 with no later issues, so vmcnt(2) at tile NT-1 would
// leave exactly its 2 loads uncertified (r5's bug: stale B1 on final K-tile).
__device__ __forceinline__ void gemm_core(const unsigned short* __restrict__ A,
                                          const unsigned short* __restrict__ BT,
                                          void* __restrict__ C, int out_f32,
                                          int m0, int n0, int cstride,
                                          int koff, int NT, char* ldsc) {
    const int t = threadIdx.x;
    const int w = t >> 6, l = t & 63;
    const int lr = l & 15, lg = l >> 4;
    const int wmh = w >> 2;              // A half select (0/1)
    const int walf = w & 3;
    const int wm = wmh << 7;             // 0/128
    const int wn = walf << 6;            // 0..192

    // frag-read constants
    const int ca0 = lg ^ (lr & 7);                       // kk=0 swizzled chunk
    const int aoff0 = lr * 128 + (ca0 << 4);             // within-slot byte, kk=0
    const int aoff1 = lr * 128 + ((ca0 ^ 4) << 4);       // kk=1
    const int boff0 = ((walf & 1) * 64 + lr) * 128 + (ca0 << 4);
    const int boff1 = ((walf & 1) * 64 + lr) * 128 + ((ca0 ^ 4) << 4);

    // stage constants: chunk c = half*512 + w*64 + l; row = c>>3,
    // swizzled ch = (l&7)^(row&7) = (l&7)^((t>>3)&7)
    const int srow = t >> 3;                              // 0..63
    const int sch = (t & 7) ^ (srow & 7);
    const size_t soff0 = (size_t)srow * 4096 + (size_t)(sch << 3);
    const size_t soff1 = soff0 + (size_t)64 * 4096;
    const int ldso = w << 10;                             // per-wave BYTE offset

    f32x4 ac[8][4];
    f32x4 vzero = {0.f, 0.f, 0.f, 0.f};
#pragma unroll
    for (int i = 0; i < 8; ++i)
#pragma unroll
        for (int j = 0; j < 4; ++j) ac[i][j] = vzero;

#define STAGE_ELEM(E, SS)                                                      \
    do {                                                                       \
        int er_ = (E) & 3;                                                     \
        const unsigned short* mb_ = (er_ < 2)                                  \
            ? A + (size_t)(m0 + ((er_ & 1) << 7)) * 4096                       \
            : BT + (size_t)(n0 + ((er_ & 1) << 7)) * 4096;                     \
        mb_ += (size_t)((((E) >> 2) << 6) + koff);                             \
        char* d0_ = ldsc + (SS) * 16384 + ldso;                                \
        GLD16(mb_ + soff0, d0_, l);                                            \
        GLD16(mb_ + soff1, d0_ + 8192, l);                                     \
    } while (0)

    // prologue: elems 0..4 in flight (10 loads/thread)
#pragma unroll
    for (int e = 0; e < 5; ++e) STAGE_ELEM(e, e);

    const int NT4 = NT << 2;
    int E = 5, ss = 5, s0 = 0;
    bf16x8 bfr[4][2];

#pragma unroll 1
    for (int tau = 0; tau < NT; ++tau) {
        int sA = s0 + wmh;          if (sA >= 9) sA -= 9;
        int sB = s0 + 2 + (walf >> 1); if (sB >= 9) sB -= 9;
        const char* pA0 = ldsc + sA * 16384 + aoff0;
        const char* pA1 = ldsc + sA * 16384 + aoff1;
        const char* pB0 = ldsc + sB * 16384 + boff0;
        const char* pB1 = ldsc + sB * 16384 + boff1;
#pragma unroll
        for (int r = 0; r < 4; ++r) {
            if (r == 0) {
                if (tau == NT - 1)
                    asm volatile("s_waitcnt vmcnt(0)" ::: "memory");
                else
                    asm volatile("s_waitcnt vmcnt(2)" ::: "memory");
            }
            __builtin_amdgcn_s_barrier();
            asm volatile("" ::: "memory");
            if (r == 0) {
#pragma unroll
                for (int nf = 0; nf < 4; ++nf) {
                    bfr[nf][0] = *(const bf16x8*)(pB0 + nf * 2048);
                    bfr[nf][1] = *(const bf16x8*)(pB1 + nf * 2048);
                }
            }
            bf16x8 af[2][2];
            int mfb = r << 1;
#pragma unroll
            for (int j = 0; j < 2; ++j) {
                af[j][0] = *(const bf16x8*)(pA0 + (mfb + j) * 2048);
                af[j][1] = *(const bf16x8*)(pA1 + (mfb + j) * 2048);
            }
            if (E < NT4) STAGE_ELEM(E, ss);
            ++E; ss = (ss == 8) ? 0 : ss + 1;
            __builtin_amdgcn_s_setprio(1);
#pragma unroll
            for (int j = 0; j < 2; ++j)
#pragma unroll
                for (int nf = 0; nf < 4; ++nf) {
                    ac[mfb + j][nf] = mfma16(af[j][0], bfr[nf][0], ac[mfb + j][nf]);
                    ac[mfb + j][nf] = mfma16(af[j][1], bfr[nf][1], ac[mfb + j][nf]);
                }
            __builtin_amdgcn_s_setprio(0);
        }
        s0 += 4; if (s0 >= 9) s0 -= 9;
    }
#undef STAGE_ELEM

    // epilogue
#pragma unroll
    for (int mf = 0; mf < 8; ++mf)
#pragma unroll
        for (int nf = 0; nf < 4; ++nf)
#pragma unroll
            for (int q = 0; q < 4; ++q) {
                int row = m0 + wm + mf * 16 + lg * 4 + q;
                int col = n0 + wn + nf * 16 + lr;
                if (out_f32)
                    ((float*)C)[(size_t)row * cstride + col] = ac[mf][nf][q];
                else
                    ((unsigned short*)C)[(size_t)row * cstride + col] = f32_to_bf16(ac[mf][nf][q]);
            }
}

// Q + fused KV in one launch: 384 blocks. newid<128 -> Q (8x16), else KV (8x32).
__global__ __launch_bounds__(512, 2) void gemm_qkv_kernel(
        const unsigned short* __restrict__ Aq, const unsigned short* __restrict__ Bq,
        unsigned short* __restrict__ Cq,
        const unsigned short* __restrict__ Akv, const unsigned short* __restrict__ Bkv,
        unsigned short* __restrict__ Ckv) {
    __shared__ char ldsbuf[9 * 16384];
    int bid = blockIdx.x;
    int newid = (bid & 7) * 48 + (bid >> 3);     // bijective: 384 = 8*48
    if (newid < 128) {
        int bm = newid >> 4, bn = newid & 15;
        gemm_core(Aq, Bq, Cq, 0, bm << 8, bn << 8, 4096, 0, 64, ldsbuf);
    } else {
        int e = newid - 128;
        int bm = e >> 5, bn = e & 31;
        gemm_core(Akv, Bkv, Ckv, 0, bm << 8, bn << 8, 8192, 0, 64, ldsbuf);
    }
}

// O GEMM split-K2: 256 blocks -> fp32 partials.
__global__ __launch_bounds__(512, 2) void gemm_o_kernel(
        const unsigned short* __restrict__ A, const unsigned short* __restrict__ BT,
        float* __restrict__ P) {
    __shared__ char ldsbuf[9 * 16384];
    int bid = blockIdx.x;
    int newid = (bid & 7) * 32 + (bid >> 3);     // bijective: 256 = 8*32
    int ks = newid >> 7;
    int tile = newid & 127;
    int bm = tile >> 4, bn = tile & 15;
    gemm_core(A, BT, P + (size_t)ks * M_ * D_, 1, bm << 8, bn << 8, 4096,
              ks * 2048, 32, ldsbuf);
}

__global__ void reduce_o_kernel(const float* __restrict__ P, float* __restrict__ out) {
    int i = blockIdx.x * 256 + threadIdx.x;      // float4 index, 2M total
    float4 a = ((const float4*)P)[i];
    float4 b = ((const float4*)(P + (size_t)M_ * D_))[i];
    float4 o; o.x = a.x + b.x; o.y = a.y + b.y; o.z = a.z + b.z; o.w = a.w + b.w;
    ((float4*)out)[i] = o;
}

// ---------------------------------------------------------------------------
// Flash attention (round-2 structure; K read from fused KV buffer, stride 8192)
#define NEGF (-1e30f)
__global__ __launch_bounds__(256, 2) void attn_kernel(const unsigned short* __restrict__ Qw,
                                                      const unsigned short* __restrict__ KV,
                                                      const unsigned short* __restrict__ Vtw,
                                                      const float* __restrict__ bias,
                                                      const unsigned char* __restrict__ maskc,
                                                      unsigned short* __restrict__ ctx) {
    __shared__ unsigned short Kbuf[2][64 * 128];
    __shared__ unsigned short Vbuf[2][128 * 64];
    __shared__ unsigned short Plds[4][16 * 72];

    int bid = blockIdx.x;
    int qt = bid & 15, h = (bid >> 4) & 31, b = bid >> 9;
    int t = threadIdx.x, w = t >> 6, l = t & 63;
    int lr = l & 15, lg = l >> 4;
    int q0 = (qt << 6) + (w << 4);

    bf16x8 qf[4];
    const unsigned short* Qp = Qw + ((size_t)(b * S_ + q0 + lr)) * D_ + h * DH_ + lg * 8;
#pragma unroll
    for (int kf = 0; kf < 4; ++kf) qf[kf] = *(const bf16x8*)(Qp + kf * 32);

    f32x4 o[8];
    f32x4 vzero = {0.f, 0.f, 0.f, 0.f};
#pragma unroll
    for (int i = 0; i < 8; ++i) o[i] = vzero;
    float m_run[4], l_run[4];
#pragma unroll
    for (int r = 0; r < 4; ++r) { m_run[r] = NEGF; l_run[r] = 0.f; }

    const float* biasp = bias + (((size_t)(b * H_ + h)) << 20)
                              + (((size_t)(q0 + (lg << 2))) << 10) + lr;
    const unsigned char* mp = maskc + ((size_t)b << 20)
                              + (((size_t)(q0 + (lg << 2))) << 10) + lr;
    const unsigned short* Kg = KV + (size_t)(b * S_) * KSTR + h * DH_;
    const unsigned short* Vg = Vtw + (((size_t)(b * H_ + h)) * DH_) * S_;

    float br0[16], br1[16];
    int mr0[16], mr1[16];

#define STAGE_KV(KT, BUF)                                                          \
    do { int kv0_ = (KT) << 6;                                                     \
        _Pragma("unroll")                                                          \
        for (int c = 0; c < 4; ++c) {                                              \
            int seg = (w << 2) + c;                                                \
            int krow = (seg << 2) + (l >> 4);                                      \
            int kch = (l & 15) ^ (krow & 7);                                       \
            GLD16(Kg + (size_t)(kv0_ + krow) * KSTR + (kch << 3),                  \
                  &Kbuf[BUF][seg << 9], l);                                        \
            int vrow = (seg << 3) + (l >> 3);                                      \
            int vch = (l & 7) ^ (vrow & 7);                                        \
            GLD16(Vg + (size_t)vrow * S_ + kv0_ + (vch << 3),                      \
                  &Vbuf[BUF][seg << 9], l);                                        \
        }                                                                          \
    } while (0)

#define LOAD_BM(BR, MR, KT)                                                        \
    do { int kv0_ = (KT) << 6;                                                     \
        _Pragma("unroll")                                                          \
        for (int nb = 0; nb < 4; ++nb)                                             \
            _Pragma("unroll")                                                      \
            for (int r = 0; r < 4; ++r) {                                          \
                BR[nb * 4 + r] = biasp[((size_t)r << 10) + kv0_ + (nb << 4)];      \
                MR[nb * 4 + r] = mp[((size_t)r << 10) + kv0_ + (nb << 4)];         \
            }                                                                      \
    } while (0)

#define COMPUTE(BUF, BR, MR)                                                       \
    do {                                                                           \
        f32x4 s_[4];                                                               \
        _Pragma("unroll")                                                          \
        for (int nb = 0; nb < 4; ++nb) {                                           \
            s_[nb] = vzero;                                                        \
            int krow = (nb << 4) + lr;                                             \
            _Pragma("unroll")                                                      \
            for (int kf = 0; kf < 4; ++kf) {                                       \
                int ba = ((krow << 8) + (((kf << 5) + (lg << 3)) << 1))            \
                         ^ ((krow & 7) << 4);                                      \
                bf16x8 kfr = *(const bf16x8*)((const char*)Kbuf[BUF] + ba);        \
                s_[nb] = mfma16(qf[kf], kfr, s_[nb]);                              \
            }                                                                      \
        }                                                                          \
        float sv[4][4];                                                            \
        _Pragma("unroll")                                                          \
        for (int nb = 0; nb < 4; ++nb)                                             \
            _Pragma("unroll")                                                      \
            for (int r = 0; r < 4; ++r) {                                          \
                float x = fmaf(s_[nb][r], 0.08838834764831845f, BR[nb * 4 + r]);   \
                sv[nb][r] = MR[nb * 4 + r] ? x : NEGF;                             \
            }                                                                      \
        float mt[4], al[4], rs[4];                                                 \
        _Pragma("unroll")                                                          \
        for (int r = 0; r < 4; ++r)                                                \
            mt[r] = fmaxf(fmaxf(sv[0][r], sv[1][r]), fmaxf(sv[2][r], sv[3][r]));   \
        _Pragma("unroll")                                                          \
        for (int off = 1; off < 16; off <<= 1)                                     \
            _Pragma("unroll")                                                      \
            for (int r = 0; r < 4; ++r) mt[r] = fmaxf(mt[r], __shfl_xor(mt[r], off, 64)); \
        _Pragma("unroll")                                                          \
        for (int r = 0; r < 4; ++r) {                                              \
            float mn = fmaxf(m_run[r], mt[r]);                                     \
            al[r] = __expf(m_run[r] - mn);                                         \
            m_run[r] = mn;                                                         \
        }                                                                          \
        _Pragma("unroll")                                                          \
        for (int nb = 0; nb < 4; ++nb)                                             \
            _Pragma("unroll")                                                      \
            for (int r = 0; r < 4; ++r) sv[nb][r] = __expf(sv[nb][r] - m_run[r]);  \
        _Pragma("unroll")                                                          \
        for (int r = 0; r < 4; ++r)                                                \
            rs[r] = (sv[0][r] + sv[1][r]) + (sv[2][r] + sv[3][r]);                 \
        _Pragma("unroll")                                                          \
        for (int off = 1; off < 16; off <<= 1)                                     \
            _Pragma("unroll")                                                      \
            for (int r = 0; r < 4; ++r) rs[r] += __shfl_xor(rs[r], off, 64);       \
        _Pragma("unroll")                                                          \
        for (int r = 0; r < 4; ++r) l_run[r] = l_run[r] * al[r] + rs[r];           \
        _Pragma("unroll")                                                          \
        for (int nb2 = 0; nb2 < 8; ++nb2) {                                        \
            o[nb2][0] *= al[0]; o[nb2][1] *= al[1];                                \
            o[nb2][2] *= al[2]; o[nb2][3] *= al[3];                                \
        }                                                                          \
        _Pragma("unroll")                                                          \
        for (int nb = 0; nb < 4; ++nb)                                             \
            _Pragma("unroll")                                                      \
            for (int r = 0; r < 4; ++r)                                            \
                Plds[w][((lg << 2) + r) * 72 + (nb << 4) + lr] = f32_to_bf16(sv[nb][r]); \
        _Pragma("unroll")                                                          \
        for (int kf2 = 0; kf2 < 2; ++kf2) {                                        \
            bf16x8 pf = *(const bf16x8*)&Plds[w][lr * 72 + (kf2 << 5) + (lg << 3)]; \
            _Pragma("unroll")                                                      \
            for (int nb2 = 0; nb2 < 8; ++nb2) {                                    \
                int dh = (nb2 << 4) + lr;                                          \
                int ba = ((dh << 7) + (((kf2 << 5) + (lg << 3)) << 1))             \
                         ^ ((dh & 7) << 4);                                        \
                bf16x8 vf = *(const bf16x8*)((const char*)Vbuf[BUF] + ba);         \
                o[nb2] = mfma16(pf, vf, o[nb2]);                                   \
            }                                                                      \
        }                                                                          \
    } while (0)

    STAGE_KV(0, 0);
    LOAD_BM(br0, mr0, 0);

#pragma unroll 1
    for (int kt = 0; kt < 16; kt += 2) {
        __syncthreads();
        STAGE_KV(kt + 1, 1);
        LOAD_BM(br1, mr1, kt + 1);
        COMPUTE(0, br0, mr0);
        __syncthreads();
        if (kt < 14) {
            STAGE_KV(kt + 2, 0);
            LOAD_BM(br0, mr0, kt + 2);
        }
        COMPUTE(1, br1, mr1);
    }

#pragma unroll
    for (int r = 0; r < 4; ++r) {
        float inv = l_run[r] > 0.f ? 1.0f / l_run[r] : 0.f;
        int q = q0 + (lg << 2) + r;
        unsigned short* cp = ctx + ((size_t)(b * S_ + q)) * D_ + h * DH_ + lr;
#pragma unroll
        for (int nb2 = 0; nb2 < 8; ++nb2)
            cp[nb2 * 16] = f32_to_bf16(o[nb2][r] * inv);
    }
#undef STAGE_KV
#undef LOAD_BM
#undef COMPUTE
}

// ---------------------------------------------------------------------------
extern "C" void kernel_launch(void* const* d_in, const int* in_sizes, int n_in,
                              void* d_out, int out_size, void* d_ws, size_t ws_size,
                              hipStream_t stream) {
    const float* hq   = (const float*)d_in[0];
    const float* hkv  = (const float*)d_in[1];
    const void*  mask = d_in[2];
    const float* bias = (const float*)d_in[3];
    const float* Wq   = (const float*)d_in[4];
    const float* Wk   = (const float*)d_in[5];
    const float* Wv   = (const float*)d_in[6];
    const float* Wo   = (const float*)d_in[7];
    float* out = (float*)d_out;

    char* ws = (char*)d_ws;
    unsigned char* mask_c = (unsigned char*)ws;                        // 2 MB
    int* flag             = (int*)(ws + (2u << 20));
    unsigned short* hq_b  = (unsigned short*)(ws + (2u << 20) + 4096); // 16 MB
    unsigned short* hkv_b = hq_b + ((size_t)1 << 23);                  // 16 MB
    unsigned short* WTq   = hkv_b + ((size_t)1 << 23);                 // 32 MB
    unsigned short* WTo   = WTq + ((size_t)1 << 24);                   // 32 MB
    unsigned short* WTkv  = WTo + ((size_t)1 << 24);                   // 64 MB
    unsigned short* Qws   = WTkv + ((size_t)1 << 25);                  // 16 MB
    unsigned short* KVws  = Qws + ((size_t)1 << 23);                   // 32 MB
    unsigned short* Cws   = KVws + ((size_t)1 << 24);                  // 16 MB
    unsigned short* Vtw   = Cws + ((size_t)1 << 23);                   // 16 MB
    float* Pws            = (float*)(Vtw + ((size_t)1 << 23));         // 64 MB

    detect_mask_kernel<<<1, 64, 0, stream>>>((const unsigned char*)mask, flag);
    canon_mask_kernel<<<8192, 256, 0, stream>>>(mask, flag, mask_c, B_ * S_ * S_);
    cvt2_bf16_kernel<<<16384, 256, 0, stream>>>(hq, hkv, hq_b, hkv_b);
    transpose_all_kernel<<<16384, 256, 0, stream>>>(Wq, Wk, Wv, Wo, WTq, WTkv, WTo);

    gemm_qkv_kernel<<<384, 512, 0, stream>>>(hq_b, WTq, Qws, hkv_b, WTkv, KVws);

    vt_kernel<<<B_ * H_ * 16 * 2, 256, 0, stream>>>(KVws, Vtw);
    attn_kernel<<<B_ * H_ * (S_ / 64), 256, 0, stream>>>(Qws, KVws, Vtw, bias, mask_c, Cws);

    gemm_o_kernel<<<256, 512, 0, stream>>>(Cws, WTo, Pws);
    reduce_o_kernel<<<(M_ * D_) / 1024, 256, 0, stream>>>(Pws, out);
}